// Round 20
// baseline (85.179 us; speedup 1.0000x reference)
//
#include <hip/hip_runtime.h>

#define Bc 2
#define Tc 384
#define Ec 768
#define Hc 12
#define HDc 64
#define TTc 8           // t-rows per score block (8 waves x 1 row)
#define SCc 64          // s-chunk staged in LDS
#define SSPLIT 3        // s-dimension split across blocks
#define SHALF (Tc / SSPLIT)          // 128 s per block
#define NCHUNK (SHALF / SCc)         // 2 chunks
#define BHT (Bc * Hc * Tc)           // 9216

typedef __attribute__((ext_vector_type(8))) short short8;
typedef __attribute__((ext_vector_type(4))) float f32x4;

#define CCONST 2.8853900817779268f   // 2*log2(e)

__device__ __forceinline__ float fexp2(float x) { return __builtin_amdgcn_exp2f(x); }
__device__ __forceinline__ float frcp(float x)  { return __builtin_amdgcn_rcpf(x); }

__device__ __forceinline__ unsigned short bf16_rne(float x) {
    unsigned u = __float_as_uint(x);
    u += 0x7fffu + ((u >> 16) & 1u);
    return (unsigned short)(u >> 16);
}
__device__ __forceinline__ float bf16_to_f(unsigned short h) {
    return __uint_as_float(((unsigned)h) << 16);
}

// ---------------------------------------------------------------------------
// prep: hs -> bf16 hi (QKV runs plain bf16);
// Wq/Wk/Wv -> transposed bf16 hi only; Wo -> transposed hi+lo.
// ---------------------------------------------------------------------------
__global__ __launch_bounds__(256) void prep_kernel(
    const float* __restrict__ hs,
    const float* __restrict__ Wq, const float* __restrict__ Wk,
    const float* __restrict__ Wv, const float* __restrict__ Wo,
    unsigned short* __restrict__ hs_hi,
    unsigned short* __restrict__ wt_hi, unsigned short* __restrict__ wt_lo)
{
    const int tid = threadIdx.x;
    int id = blockIdx.x;
    if (id < 144) {
        int base = id * 4096 + tid * 16;
#pragma unroll
        for (int i = 0; i < 4; ++i) {
            float4 x = *reinterpret_cast<const float4*>(&hs[base + i * 4]);
            ushort4 hv;
            hv.x = bf16_rne(x.x);
            hv.y = bf16_rne(x.y);
            hv.z = bf16_rne(x.z);
            hv.w = bf16_rne(x.w);
            *reinterpret_cast<ushort4*>(&hs_hi[base + i * 4]) = hv;
        }
    } else {
        id -= 144;
        const int w = id / 144, t = id % 144;
        const int tr = t / 12, tc2 = t % 12;
        const float* W = (w == 0) ? Wq : (w == 1) ? Wk : (w == 2) ? Wv : Wo;
        unsigned short* TH = wt_hi + (size_t)w * Ec * Ec;
        unsigned short* TL = wt_lo + (size_t)w * Ec * Ec;

        __shared__ float tile[64][68];
        const int r = tid >> 2, c0 = (tid & 3) * 16;
#pragma unroll
        for (int i = 0; i < 4; ++i)
            *reinterpret_cast<float4*>(&tile[r][c0 + i * 4]) =
                *reinterpret_cast<const float4*>(&W[(tr * 64 + r) * Ec + tc2 * 64 + c0 + i * 4]);
        __syncthreads();
        const int n = tid >> 2, k0 = (tid & 3) * 4;
#pragma unroll
        for (int i = 0; i < 4; ++i) {
            int k = k0 + i * 16;
            float v0 = tile[k + 0][n], v1 = tile[k + 1][n];
            float v2 = tile[k + 2][n], v3 = tile[k + 3][n];
            ushort4 hv;
            hv.x = bf16_rne(v0);
            hv.y = bf16_rne(v1);
            hv.z = bf16_rne(v2);
            hv.w = bf16_rne(v3);
            size_t off = (size_t)(tc2 * 64 + n) * Ec + tr * 64 + k;
            *reinterpret_cast<ushort4*>(&TH[off]) = hv;
            if (w == 3) {
                ushort4 lv;
                lv.x = bf16_rne(v0 - bf16_to_f(hv.x));
                lv.y = bf16_rne(v1 - bf16_to_f(hv.y));
                lv.z = bf16_rne(v2 - bf16_to_f(hv.z));
                lv.w = bf16_rne(v3 - bf16_to_f(hv.w));
                *reinterpret_cast<ushort4*>(&TL[off]) = lv;
            }
        }
    }
}

// ---------------------------------------------------------------------------
// QKV GEMM, PLAIN bf16.
//   z==0: EQ = exp2(cc*(A@W+b))  fp32 row-major
//   z==1: EK = exp2(cc*(A@W+b))  fp32 row-major
//   z==2: Vt = (A@W+b) TRANSPOSED bf16 [bh][d][s]
// ---------------------------------------------------------------------------
__global__ __launch_bounds__(256) void gemm_qkv(
    const unsigned short* __restrict__ Ahi,
    const unsigned short* __restrict__ Bh0,
    const unsigned short* __restrict__ Bh1,
    const unsigned short* __restrict__ Bh2,
    const float* __restrict__ b0, const float* __restrict__ b1, const float* __restrict__ b2,
    float* __restrict__ C0, float* __restrict__ C1,
    unsigned short* __restrict__ Vt)
{
    const int z = blockIdx.z;
    const unsigned short* Bhi = (z == 0) ? Bh0 : (z == 1) ? Bh1 : Bh2;
    const float* bias = (z == 0) ? b0 : (z == 1) ? b1 : b2;

    __shared__ __align__(16) short sAh[64][72], sBh[64][72];

    const int tid = threadIdx.x;
    const int m0 = blockIdx.y * 64, n0 = blockIdx.x * 64;
    const int wave = tid >> 6, lane = tid & 63;
    const int wm = (wave >> 1) * 32, wn = (wave & 1) * 32;
    const int fr = lane & 15, fk = (lane >> 4) * 8;
    const int sr = tid >> 3, sg = (tid & 7) * 8;

    f32x4 zero = {0.f, 0.f, 0.f, 0.f};
    f32x4 acc[2][2];
    acc[0][0] = zero; acc[0][1] = zero; acc[1][0] = zero; acc[1][1] = zero;

    for (int kc = 0; kc < Ec; kc += 64) {
        int4 a0 = *reinterpret_cast<const int4*>(&Ahi[(size_t)(m0 + sr) * Ec + kc + sg]);
        int4 a1 = *reinterpret_cast<const int4*>(&Ahi[(size_t)(m0 + sr + 32) * Ec + kc + sg]);
        int4 w0 = *reinterpret_cast<const int4*>(&Bhi[(size_t)(n0 + sr) * Ec + kc + sg]);
        int4 w1 = *reinterpret_cast<const int4*>(&Bhi[(size_t)(n0 + sr + 32) * Ec + kc + sg]);
        __syncthreads();
        *reinterpret_cast<int4*>(&sAh[sr][sg])      = a0;
        *reinterpret_cast<int4*>(&sAh[sr + 32][sg]) = a1;
        *reinterpret_cast<int4*>(&sBh[sr][sg])      = w0;
        *reinterpret_cast<int4*>(&sBh[sr + 32][sg]) = w1;
        __syncthreads();

#pragma unroll
        for (int ks = 0; ks < 64; ks += 32) {
            short8 ah[2], bh[2];
#pragma unroll
            for (int mi = 0; mi < 2; ++mi)
                ah[mi] = *reinterpret_cast<const short8*>(&sAh[wm + mi * 16 + fr][ks + fk]);
#pragma unroll
            for (int ni = 0; ni < 2; ++ni)
                bh[ni] = *reinterpret_cast<const short8*>(&sBh[wn + ni * 16 + fr][ks + fk]);
#pragma unroll
            for (int mi = 0; mi < 2; ++mi)
#pragma unroll
                for (int ni = 0; ni < 2; ++ni)
                    acc[mi][ni] = __builtin_amdgcn_mfma_f32_16x16x32_bf16(ah[mi], bh[ni], acc[mi][ni], 0, 0, 0);
        }
        __syncthreads();
    }

    const int rbase = (lane >> 4) * 4;
#pragma unroll
    for (int ni = 0; ni < 2; ++ni) {
        const int cn = n0 + wn + ni * 16 + fr;
        const float bsv = bias[cn];
#pragma unroll
        for (int mi = 0; mi < 2; ++mi) {
            const int rm = m0 + wm + mi * 16 + rbase;
            if (z == 2) {
                const int bb = rm / Tc, ss = rm % Tc;
                const int hh = cn >> 6, dd = cn & 63;
                ushort4 pk;
                pk.x = bf16_rne(acc[mi][ni][0] + bsv);
                pk.y = bf16_rne(acc[mi][ni][1] + bsv);
                pk.z = bf16_rne(acc[mi][ni][2] + bsv);
                pk.w = bf16_rne(acc[mi][ni][3] + bsv);
                *reinterpret_cast<ushort4*>(
                    &Vt[((size_t)(bb * Hc + hh) * HDc + dd) * Tc + ss]) = pk;
            } else {
                float* C = (z == 0) ? C0 : C1;
#pragma unroll
                for (int rr = 0; rr < 4; ++rr)
                    C[(size_t)(rm + rr) * Ec + cn] = fexp2((acc[mi][ni][rr] + bsv) * CCONST);
            }
        }
    }
}

// ---------------------------------------------------------------------------
// Output GEMM, split-bf16 3-product, K-SPLIT across blockIdx.z (2 halves,
// 288 blocks): partials into Cp[z] (aliases dead EQ/EK buffers).
// ---------------------------------------------------------------------------
__global__ __launch_bounds__(256) void gemm_out(
    const unsigned short* __restrict__ Ahi, const unsigned short* __restrict__ Alo,
    const unsigned short* __restrict__ Bhi, const unsigned short* __restrict__ Blo,
    float* __restrict__ Cp)
{
    __shared__ __align__(16) short sAh[64][72], sAl[64][72], sBh[64][72], sBl[64][72];

    const int tid = threadIdx.x;
    const int m0 = blockIdx.y * 64, n0 = blockIdx.x * 64;
    const int kc0 = blockIdx.z * (Ec / 2);
    const int wave = tid >> 6, lane = tid & 63;
    const int wm = (wave >> 1) * 32, wn = (wave & 1) * 32;
    const int fr = lane & 15, fk = (lane >> 4) * 8;
    const int sr = tid >> 3, sg = (tid & 7) * 8;

    f32x4 zero = {0.f, 0.f, 0.f, 0.f};
    f32x4 acc[2][2];
    acc[0][0] = zero; acc[0][1] = zero; acc[1][0] = zero; acc[1][1] = zero;

    for (int kc = kc0; kc < kc0 + Ec / 2; kc += 64) {
        int4 a0 = *reinterpret_cast<const int4*>(&Ahi[(size_t)(m0 + sr) * Ec + kc + sg]);
        int4 a1 = *reinterpret_cast<const int4*>(&Ahi[(size_t)(m0 + sr + 32) * Ec + kc + sg]);
        int4 a2 = *reinterpret_cast<const int4*>(&Alo[(size_t)(m0 + sr) * Ec + kc + sg]);
        int4 a3 = *reinterpret_cast<const int4*>(&Alo[(size_t)(m0 + sr + 32) * Ec + kc + sg]);
        int4 w0 = *reinterpret_cast<const int4*>(&Bhi[(size_t)(n0 + sr) * Ec + kc + sg]);
        int4 w1 = *reinterpret_cast<const int4*>(&Bhi[(size_t)(n0 + sr + 32) * Ec + kc + sg]);
        int4 w2 = *reinterpret_cast<const int4*>(&Blo[(size_t)(n0 + sr) * Ec + kc + sg]);
        int4 w3 = *reinterpret_cast<const int4*>(&Blo[(size_t)(n0 + sr + 32) * Ec + kc + sg]);
        __syncthreads();
        *reinterpret_cast<int4*>(&sAh[sr][sg])      = a0;
        *reinterpret_cast<int4*>(&sAh[sr + 32][sg]) = a1;
        *reinterpret_cast<int4*>(&sAl[sr][sg])      = a2;
        *reinterpret_cast<int4*>(&sAl[sr + 32][sg]) = a3;
        *reinterpret_cast<int4*>(&sBh[sr][sg])      = w0;
        *reinterpret_cast<int4*>(&sBh[sr + 32][sg]) = w1;
        *reinterpret_cast<int4*>(&sBl[sr][sg])      = w2;
        *reinterpret_cast<int4*>(&sBl[sr + 32][sg]) = w3;
        __syncthreads();

#pragma unroll
        for (int ks = 0; ks < 64; ks += 32) {
            short8 ah[2], al[2], bh[2], bl[2];
#pragma unroll
            for (int mi = 0; mi < 2; ++mi) {
                ah[mi] = *reinterpret_cast<const short8*>(&sAh[wm + mi * 16 + fr][ks + fk]);
                al[mi] = *reinterpret_cast<const short8*>(&sAl[wm + mi * 16 + fr][ks + fk]);
            }
#pragma unroll
            for (int ni = 0; ni < 2; ++ni) {
                bh[ni] = *reinterpret_cast<const short8*>(&sBh[wn + ni * 16 + fr][ks + fk]);
                bl[ni] = *reinterpret_cast<const short8*>(&sBl[wn + ni * 16 + fr][ks + fk]);
            }
#pragma unroll
            for (int mi = 0; mi < 2; ++mi)
#pragma unroll
                for (int ni = 0; ni < 2; ++ni) {
                    acc[mi][ni] = __builtin_amdgcn_mfma_f32_16x16x32_bf16(ah[mi], bh[ni], acc[mi][ni], 0, 0, 0);
                    acc[mi][ni] = __builtin_amdgcn_mfma_f32_16x16x32_bf16(ah[mi], bl[ni], acc[mi][ni], 0, 0, 0);
                    acc[mi][ni] = __builtin_amdgcn_mfma_f32_16x16x32_bf16(al[mi], bh[ni], acc[mi][ni], 0, 0, 0);
                }
        }
        __syncthreads();
    }

    float* C = Cp + (size_t)blockIdx.z * (size_t)(Bc * Tc) * Ec;
    const int rbase = (lane >> 4) * 4;
#pragma unroll
    for (int ni = 0; ni < 2; ++ni) {
        const int cn = n0 + wn + ni * 16 + fr;
#pragma unroll
        for (int mi = 0; mi < 2; ++mi) {
            const int rm = m0 + wm + mi * 16 + rbase;
#pragma unroll
            for (int rr = 0; rr < 4; ++rr)
                C[(size_t)(rm + rr) * Ec + cn] = acc[mi][ni][rr];
        }
    }
}

// out = Cp0 + Cp1 + bias  (memory-bound, 576 blocks)
__global__ __launch_bounds__(256) void addbias_kernel(
    const float* __restrict__ Cp, const float* __restrict__ bias,
    float* __restrict__ out)
{
    const size_t MAT = (size_t)(Bc * Tc) * Ec;
    int i = blockIdx.x * 1024 + threadIdx.x * 4;
    float4 a = *reinterpret_cast<const float4*>(&Cp[i]);
    float4 b = *reinterpret_cast<const float4*>(&Cp[MAT + i]);
    float4 bs = *reinterpret_cast<const float4*>(&bias[i % Ec]);
    float4 r;
    r.x = a.x + b.x + bs.x;
    r.y = a.y + b.y + bs.y;
    r.z = a.z + b.z + bs.z;
    r.w = a.w + b.w + bs.w;
    *reinterpret_cast<float4*>(&out[i]) = r;
}

// ---------------------------------------------------------------------------
// score+softmax: S = sum_d w_d * rcp(1 + EQ*EK). 512 threads = 8 waves,
// ONE t-row per wave; the wave's 64 q-values live in 16 float4 REGISTERS
// (one-time broadcast load from EQ) -> inner loop issues only 1 LDS b128
// (k4) per d4-iter. blockIdx.z splits s into thirds. Partial row sums ->
// Rpart[z]; pv adds all three (deterministic).
// ---------------------------------------------------------------------------
__global__ __launch_bounds__(512) void score_softmax_kernel(
    const float* __restrict__ EQ, const float* __restrict__ EK,
    const float* __restrict__ w_score,
    unsigned short* __restrict__ Pg, float* __restrict__ Rpart)
{
    const int bh = blockIdx.x;
    const int b = bh / Hc, h = bh % Hc;
    const int t0 = blockIdx.y * TTc;
    const int sbase = blockIdx.z * SHALF;
    const int tid = threadIdx.x;
    const int wave = tid >> 6, lane = tid & 63;
    const int trow = t0 + wave;

    __shared__ float kv[SCc][HDc + 4];        // 17 KB (EK chunk, natural [s][d])

    // wave's q row -> 16 float4 registers (all lanes same addr -> broadcast)
    const float* qr = EQ + (size_t)(b * Tc + trow) * Ec + h * HDc;
    float4 q[16];
#pragma unroll
    for (int i = 0; i < 16; ++i)
        q[i] = *reinterpret_cast<const float4*>(qr + i * 4);

    unsigned short* dst = &Pg[((size_t)bh * Tc + trow) * Tc + sbase + lane];
    float sum = 0.f;

    for (int c = 0; c < NCHUNK; ++c) {
        const int s0 = sbase + c * SCc;
        if (c > 0) __syncthreads();
        // staging: 1024 float4 over 512 threads = 2 per thread
#pragma unroll
        for (int i = 0; i < 2; ++i) {
            int id = i * 512 + tid;
            int srr = id >> 4, d4 = (id & 15) << 2;
            float4 kvv = *reinterpret_cast<const float4*>(
                &EK[(size_t)(b * Tc + s0 + srr) * Ec + h * HDc + d4]);
            *reinterpret_cast<float4*>(&kv[srr][d4]) = kvv;
        }
        __syncthreads();
        float a = 0.f;
#pragma unroll
        for (int d4 = 0; d4 < 16; ++d4) {
            float4 k4 = *reinterpret_cast<const float4*>(&kv[lane][d4 * 4]);
            a = fmaf(w_score[d4 * 4 + 0], frcp(fmaf(q[d4].x, k4.x, 1.f)), a);
            a = fmaf(w_score[d4 * 4 + 1], frcp(fmaf(q[d4].y, k4.y, 1.f)), a);
            a = fmaf(w_score[d4 * 4 + 2], frcp(fmaf(q[d4].z, k4.z, 1.f)), a);
            a = fmaf(w_score[d4 * 4 + 3], frcp(fmaf(q[d4].w, k4.w, 1.f)), a);
        }
        // p = exp(-2S) = exp2(-S*cc); bounded in [2^-3, 2^3] -> no max pass
        float p = fexp2(-a * CCONST);
        dst[c * SCc] = bf16_rne(p);
        sum += p;
    }

    // partial row sum via wave butterfly; lane 0 writes this third's sum
#pragma unroll
    for (int off = 32; off > 0; off >>= 1) sum += __shfl_xor(sum, off, 64);
    if (lane == 0)
        Rpart[(size_t)blockIdx.z * BHT + bh * Tc + trow] = sum;
}

// ---------------------------------------------------------------------------
// PV via MFMA on UNNORMALIZED p: out[t][d] = sum_s p*V / (sum of 3 Rparts).
// Per block 64t x 64d, 4 waves = m-split, no LDS. Emits ATT bf16 hi/lo.
// ---------------------------------------------------------------------------
__global__ __launch_bounds__(256) void pv_mfma(
    const unsigned short* __restrict__ Pg, const unsigned short* __restrict__ Vt,
    const float* __restrict__ Rpart,
    unsigned short* __restrict__ Ohi, unsigned short* __restrict__ Olo)
{
    const int bh = blockIdx.x;
    const int b = bh / Hc, h = bh % Hc;
    const int tt = blockIdx.y;  // 0..5
    const int tid = threadIdx.x;
    const int wave = tid >> 6, lane = tid & 63;
    const int fr = lane & 15, fk = (lane >> 4) * 8;

    const unsigned short* Pbase = Pg + ((size_t)bh * Tc + tt * 64 + wave * 16 + fr) * Tc + fk;
    const unsigned short* Vbase = Vt + (size_t)bh * HDc * Tc + fk;

    f32x4 zero = {0.f, 0.f, 0.f, 0.f};
    f32x4 acc[4];
    acc[0] = zero; acc[1] = zero; acc[2] = zero; acc[3] = zero;

    for (int ks = 0; ks < Tc; ks += 32) {
        short8 af = *reinterpret_cast<const short8*>(Pbase + ks);
#pragma unroll
        for (int ni = 0; ni < 4; ++ni) {
            short8 bf = *reinterpret_cast<const short8*>(
                Vbase + (size_t)(ni * 16 + fr) * Tc + ks);
            acc[ni] = __builtin_amdgcn_mfma_f32_16x16x32_bf16(af, bf, acc[ni], 0, 0, 0);
        }
    }

    const int rbase = (lane >> 4) * 4;
    float rv[4];
#pragma unroll
    for (int rr = 0; rr < 4; ++rr) {
        size_t ridx = (size_t)bh * Tc + tt * 64 + wave * 16 + rbase + rr;
        rv[rr] = frcp(Rpart[ridx] + Rpart[ridx + BHT] + Rpart[ridx + 2 * BHT]);
    }

#pragma unroll
    for (int ni = 0; ni < 4; ++ni) {
#pragma unroll
        for (int rr = 0; rr < 4; ++rr) {
            int t_out = tt * 64 + wave * 16 + rbase + rr;
            float x = acc[ni][rr] * rv[rr];
            unsigned short hb = bf16_rne(x);
            unsigned short lb = bf16_rne(x - bf16_to_f(hb));
            size_t idx = (size_t)(b * Tc + t_out) * Ec + h * HDc + ni * 16 + fr;
            Ohi[idx] = hb;
            Olo[idx] = lb;
        }
    }
}

extern "C" void kernel_launch(void* const* d_in, const int* in_sizes, int n_in,
                              void* d_out, int out_size, void* d_ws, size_t ws_size,
                              hipStream_t stream) {
    const float* hs  = (const float*)d_in[0];
    const float* Wq  = (const float*)d_in[1];
    const float* bq  = (const float*)d_in[2];
    const float* Wk  = (const float*)d_in[3];
    const float* bk  = (const float*)d_in[4];
    const float* Wv  = (const float*)d_in[5];
    const float* bv  = (const float*)d_in[6];
    const float* Wo  = (const float*)d_in[7];
    const float* bo  = (const float*)d_in[8];
    const float* wsc = (const float*)d_in[9];
    float* out = (float*)d_out;

    const size_t MAT = (size_t)(Bc * Tc) * Ec;           // 589824
    const size_t PSZ = (size_t)Bc * Hc * Tc * Tc;        // 3538944
    float* EQw = (float*)d_ws;                           // exp2(cc*q); later Cpart[0]
    float* EKw = EQw + MAT;                              // exp2(cc*k); later Cpart[1]
    float* Rpart = EKw + MAT;                            // partial rowsums, 3 x BHT
    unsigned short* Vt    = (unsigned short*)(Rpart + 3 * (size_t)BHT);
    unsigned short* Pgb   = Vt + MAT;
    unsigned short* HS_HI = Pgb + PSZ;
    unsigned short* HS_LO = HS_HI + MAT;                 // reused as ATT hi/lo
    unsigned short* WT_HI = HS_LO + MAT;
    unsigned short* WT_LO = WT_HI + 4 * MAT;

    prep_kernel<<<720, 256, 0, stream>>>(hs, Wq, Wk, Wv, Wo, HS_HI, WT_HI, WT_LO);

    gemm_qkv<<<dim3(Ec / 64, (Bc * Tc) / 64, 3), 256, 0, stream>>>(
        HS_HI,
        WT_HI + 0 * MAT, WT_HI + 1 * MAT, WT_HI + 2 * MAT,
        bq, bk, bv, EQw, EKw, Vt);

    score_softmax_kernel<<<dim3(Bc * Hc, Tc / TTc, SSPLIT), 512, 0, stream>>>(
        EQw, EKw, wsc, Pgb, Rpart);

    pv_mfma<<<dim3(Bc * Hc, Tc / 64), 256, 0, stream>>>(Pgb, Vt, Rpart, HS_HI, HS_LO);

    // EQ/EK are dead now; reuse their 2*MAT floats as the K-split partials.
    gemm_out<<<dim3(Ec / 64, (Bc * Tc) / 64, 2), 256, 0, stream>>>(
        HS_HI, HS_LO,
        WT_HI + 3 * MAT, WT_LO + 3 * MAT,
        EQw);

    addbias_kernel<<<(int)(MAT / 1024), 256, 0, stream>>>(EQw, bo, out);
}

// Round 21
// 73.503 us; speedup vs baseline: 1.1589x; 1.1589x over previous
//
#include <hip/hip_runtime.h>

#define Bc 2
#define Tc 384
#define Ec 768
#define Hc 12
#define HDc 64
#define TTc 8           // t-rows per score block
#define SCc 64          // s-chunk staged in LDS
#define SSPLIT 3        // s-dimension split across blocks
#define SHALF (Tc / SSPLIT)          // 128 s per block
#define NCHUNK (SHALF / SCc)         // 2 chunks
#define BHT (Bc * Hc * Tc)           // 9216

typedef __attribute__((ext_vector_type(8))) short short8;
typedef __attribute__((ext_vector_type(4))) float f32x4;

#define CCONST 2.8853900817779268f   // 2*log2(e)

__device__ __forceinline__ float fexp2(float x) { return __builtin_amdgcn_exp2f(x); }
__device__ __forceinline__ float frcp(float x)  { return __builtin_amdgcn_rcpf(x); }

__device__ __forceinline__ unsigned short bf16_rne(float x) {
    unsigned u = __float_as_uint(x);
    u += 0x7fffu + ((u >> 16) & 1u);
    return (unsigned short)(u >> 16);
}
__device__ __forceinline__ float bf16_to_f(unsigned short h) {
    return __uint_as_float(((unsigned)h) << 16);
}

// ---------------------------------------------------------------------------
// prep: hs -> bf16 hi (QKV runs plain bf16);
// Wq/Wk/Wv -> transposed bf16 hi only; Wo -> transposed hi+lo.
// ---------------------------------------------------------------------------
__global__ __launch_bounds__(256) void prep_kernel(
    const float* __restrict__ hs,
    const float* __restrict__ Wq, const float* __restrict__ Wk,
    const float* __restrict__ Wv, const float* __restrict__ Wo,
    unsigned short* __restrict__ hs_hi,
    unsigned short* __restrict__ wt_hi, unsigned short* __restrict__ wt_lo)
{
    const int tid = threadIdx.x;
    int id = blockIdx.x;
    if (id < 144) {
        int base = id * 4096 + tid * 16;
#pragma unroll
        for (int i = 0; i < 4; ++i) {
            float4 x = *reinterpret_cast<const float4*>(&hs[base + i * 4]);
            ushort4 hv;
            hv.x = bf16_rne(x.x);
            hv.y = bf16_rne(x.y);
            hv.z = bf16_rne(x.z);
            hv.w = bf16_rne(x.w);
            *reinterpret_cast<ushort4*>(&hs_hi[base + i * 4]) = hv;
        }
    } else {
        id -= 144;
        const int w = id / 144, t = id % 144;
        const int tr = t / 12, tc2 = t % 12;
        const float* W = (w == 0) ? Wq : (w == 1) ? Wk : (w == 2) ? Wv : Wo;
        unsigned short* TH = wt_hi + (size_t)w * Ec * Ec;
        unsigned short* TL = wt_lo + (size_t)w * Ec * Ec;

        __shared__ float tile[64][68];
        const int r = tid >> 2, c0 = (tid & 3) * 16;
#pragma unroll
        for (int i = 0; i < 4; ++i)
            *reinterpret_cast<float4*>(&tile[r][c0 + i * 4]) =
                *reinterpret_cast<const float4*>(&W[(tr * 64 + r) * Ec + tc2 * 64 + c0 + i * 4]);
        __syncthreads();
        const int n = tid >> 2, k0 = (tid & 3) * 4;
#pragma unroll
        for (int i = 0; i < 4; ++i) {
            int k = k0 + i * 16;
            float v0 = tile[k + 0][n], v1 = tile[k + 1][n];
            float v2 = tile[k + 2][n], v3 = tile[k + 3][n];
            ushort4 hv;
            hv.x = bf16_rne(v0);
            hv.y = bf16_rne(v1);
            hv.z = bf16_rne(v2);
            hv.w = bf16_rne(v3);
            size_t off = (size_t)(tc2 * 64 + n) * Ec + tr * 64 + k;
            *reinterpret_cast<ushort4*>(&TH[off]) = hv;
            if (w == 3) {
                ushort4 lv;
                lv.x = bf16_rne(v0 - bf16_to_f(hv.x));
                lv.y = bf16_rne(v1 - bf16_to_f(hv.y));
                lv.z = bf16_rne(v2 - bf16_to_f(hv.z));
                lv.w = bf16_rne(v3 - bf16_to_f(hv.w));
                *reinterpret_cast<ushort4*>(&TL[off]) = lv;
            }
        }
    }
}

// ---------------------------------------------------------------------------
// QKV GEMM, PLAIN bf16.
//   z==0: EQ = exp2(cc*(A@W+b))  fp32 row-major
//   z==1: EK = exp2(cc*(A@W+b))  fp32 row-major
//   z==2: Vt = (A@W+b) TRANSPOSED bf16 [bh][d][s]
// ---------------------------------------------------------------------------
__global__ __launch_bounds__(256) void gemm_qkv(
    const unsigned short* __restrict__ Ahi,
    const unsigned short* __restrict__ Bh0,
    const unsigned short* __restrict__ Bh1,
    const unsigned short* __restrict__ Bh2,
    const float* __restrict__ b0, const float* __restrict__ b1, const float* __restrict__ b2,
    float* __restrict__ C0, float* __restrict__ C1,
    unsigned short* __restrict__ Vt)
{
    const int z = blockIdx.z;
    const unsigned short* Bhi = (z == 0) ? Bh0 : (z == 1) ? Bh1 : Bh2;
    const float* bias = (z == 0) ? b0 : (z == 1) ? b1 : b2;

    __shared__ __align__(16) short sAh[64][72], sBh[64][72];

    const int tid = threadIdx.x;
    const int m0 = blockIdx.y * 64, n0 = blockIdx.x * 64;
    const int wave = tid >> 6, lane = tid & 63;
    const int wm = (wave >> 1) * 32, wn = (wave & 1) * 32;
    const int fr = lane & 15, fk = (lane >> 4) * 8;
    const int sr = tid >> 3, sg = (tid & 7) * 8;

    f32x4 zero = {0.f, 0.f, 0.f, 0.f};
    f32x4 acc[2][2];
    acc[0][0] = zero; acc[0][1] = zero; acc[1][0] = zero; acc[1][1] = zero;

    for (int kc = 0; kc < Ec; kc += 64) {
        int4 a0 = *reinterpret_cast<const int4*>(&Ahi[(size_t)(m0 + sr) * Ec + kc + sg]);
        int4 a1 = *reinterpret_cast<const int4*>(&Ahi[(size_t)(m0 + sr + 32) * Ec + kc + sg]);
        int4 w0 = *reinterpret_cast<const int4*>(&Bhi[(size_t)(n0 + sr) * Ec + kc + sg]);
        int4 w1 = *reinterpret_cast<const int4*>(&Bhi[(size_t)(n0 + sr + 32) * Ec + kc + sg]);
        __syncthreads();
        *reinterpret_cast<int4*>(&sAh[sr][sg])      = a0;
        *reinterpret_cast<int4*>(&sAh[sr + 32][sg]) = a1;
        *reinterpret_cast<int4*>(&sBh[sr][sg])      = w0;
        *reinterpret_cast<int4*>(&sBh[sr + 32][sg]) = w1;
        __syncthreads();

#pragma unroll
        for (int ks = 0; ks < 64; ks += 32) {
            short8 ah[2], bh[2];
#pragma unroll
            for (int mi = 0; mi < 2; ++mi)
                ah[mi] = *reinterpret_cast<const short8*>(&sAh[wm + mi * 16 + fr][ks + fk]);
#pragma unroll
            for (int ni = 0; ni < 2; ++ni)
                bh[ni] = *reinterpret_cast<const short8*>(&sBh[wn + ni * 16 + fr][ks + fk]);
#pragma unroll
            for (int mi = 0; mi < 2; ++mi)
#pragma unroll
                for (int ni = 0; ni < 2; ++ni)
                    acc[mi][ni] = __builtin_amdgcn_mfma_f32_16x16x32_bf16(ah[mi], bh[ni], acc[mi][ni], 0, 0, 0);
        }
        __syncthreads();
    }

    const int rbase = (lane >> 4) * 4;
#pragma unroll
    for (int ni = 0; ni < 2; ++ni) {
        const int cn = n0 + wn + ni * 16 + fr;
        const float bsv = bias[cn];
#pragma unroll
        for (int mi = 0; mi < 2; ++mi) {
            const int rm = m0 + wm + mi * 16 + rbase;
            if (z == 2) {
                const int bb = rm / Tc, ss = rm % Tc;
                const int hh = cn >> 6, dd = cn & 63;
                ushort4 pk;
                pk.x = bf16_rne(acc[mi][ni][0] + bsv);
                pk.y = bf16_rne(acc[mi][ni][1] + bsv);
                pk.z = bf16_rne(acc[mi][ni][2] + bsv);
                pk.w = bf16_rne(acc[mi][ni][3] + bsv);
                *reinterpret_cast<ushort4*>(
                    &Vt[((size_t)(bb * Hc + hh) * HDc + dd) * Tc + ss]) = pk;
            } else {
                float* C = (z == 0) ? C0 : C1;
#pragma unroll
                for (int rr = 0; rr < 4; ++rr)
                    C[(size_t)(rm + rr) * Ec + cn] = fexp2((acc[mi][ni][rr] + bsv) * CCONST);
            }
        }
    }
}

// ---------------------------------------------------------------------------
// Output GEMM, split-bf16 3-product, K-SPLIT across blockIdx.z (2 halves,
// 288 blocks): each z computes a partial over K in [z*384, z*384+384) into
// Cp[z]. addbias_kernel sums the halves + bias (all fp32, deterministic).
// Cp aliases the dead EQ/EK buffers (no extra workspace).
// ---------------------------------------------------------------------------
__global__ __launch_bounds__(256) void gemm_out(
    const unsigned short* __restrict__ Ahi, const unsigned short* __restrict__ Alo,
    const unsigned short* __restrict__ Bhi, const unsigned short* __restrict__ Blo,
    float* __restrict__ Cp)
{
    __shared__ __align__(16) short sAh[64][72], sAl[64][72], sBh[64][72], sBl[64][72];

    const int tid = threadIdx.x;
    const int m0 = blockIdx.y * 64, n0 = blockIdx.x * 64;
    const int kc0 = blockIdx.z * (Ec / 2);
    const int wave = tid >> 6, lane = tid & 63;
    const int wm = (wave >> 1) * 32, wn = (wave & 1) * 32;
    const int fr = lane & 15, fk = (lane >> 4) * 8;
    const int sr = tid >> 3, sg = (tid & 7) * 8;

    f32x4 zero = {0.f, 0.f, 0.f, 0.f};
    f32x4 acc[2][2];
    acc[0][0] = zero; acc[0][1] = zero; acc[1][0] = zero; acc[1][1] = zero;

    for (int kc = kc0; kc < kc0 + Ec / 2; kc += 64) {
        int4 a0 = *reinterpret_cast<const int4*>(&Ahi[(size_t)(m0 + sr) * Ec + kc + sg]);
        int4 a1 = *reinterpret_cast<const int4*>(&Ahi[(size_t)(m0 + sr + 32) * Ec + kc + sg]);
        int4 a2 = *reinterpret_cast<const int4*>(&Alo[(size_t)(m0 + sr) * Ec + kc + sg]);
        int4 a3 = *reinterpret_cast<const int4*>(&Alo[(size_t)(m0 + sr + 32) * Ec + kc + sg]);
        int4 w0 = *reinterpret_cast<const int4*>(&Bhi[(size_t)(n0 + sr) * Ec + kc + sg]);
        int4 w1 = *reinterpret_cast<const int4*>(&Bhi[(size_t)(n0 + sr + 32) * Ec + kc + sg]);
        int4 w2 = *reinterpret_cast<const int4*>(&Blo[(size_t)(n0 + sr) * Ec + kc + sg]);
        int4 w3 = *reinterpret_cast<const int4*>(&Blo[(size_t)(n0 + sr + 32) * Ec + kc + sg]);
        __syncthreads();
        *reinterpret_cast<int4*>(&sAh[sr][sg])      = a0;
        *reinterpret_cast<int4*>(&sAh[sr + 32][sg]) = a1;
        *reinterpret_cast<int4*>(&sAl[sr][sg])      = a2;
        *reinterpret_cast<int4*>(&sAl[sr + 32][sg]) = a3;
        *reinterpret_cast<int4*>(&sBh[sr][sg])      = w0;
        *reinterpret_cast<int4*>(&sBh[sr + 32][sg]) = w1;
        *reinterpret_cast<int4*>(&sBl[sr][sg])      = w2;
        *reinterpret_cast<int4*>(&sBl[sr + 32][sg]) = w3;
        __syncthreads();

#pragma unroll
        for (int ks = 0; ks < 64; ks += 32) {
            short8 ah[2], al[2], bh[2], bl[2];
#pragma unroll
            for (int mi = 0; mi < 2; ++mi) {
                ah[mi] = *reinterpret_cast<const short8*>(&sAh[wm + mi * 16 + fr][ks + fk]);
                al[mi] = *reinterpret_cast<const short8*>(&sAl[wm + mi * 16 + fr][ks + fk]);
            }
#pragma unroll
            for (int ni = 0; ni < 2; ++ni) {
                bh[ni] = *reinterpret_cast<const short8*>(&sBh[wn + ni * 16 + fr][ks + fk]);
                bl[ni] = *reinterpret_cast<const short8*>(&sBl[wn + ni * 16 + fr][ks + fk]);
            }
#pragma unroll
            for (int mi = 0; mi < 2; ++mi)
#pragma unroll
                for (int ni = 0; ni < 2; ++ni) {
                    acc[mi][ni] = __builtin_amdgcn_mfma_f32_16x16x32_bf16(ah[mi], bh[ni], acc[mi][ni], 0, 0, 0);
                    acc[mi][ni] = __builtin_amdgcn_mfma_f32_16x16x32_bf16(ah[mi], bl[ni], acc[mi][ni], 0, 0, 0);
                    acc[mi][ni] = __builtin_amdgcn_mfma_f32_16x16x32_bf16(al[mi], bh[ni], acc[mi][ni], 0, 0, 0);
                }
        }
        __syncthreads();
    }

    float* C = Cp + (size_t)blockIdx.z * (size_t)(Bc * Tc) * Ec;
    const int rbase = (lane >> 4) * 4;
#pragma unroll
    for (int ni = 0; ni < 2; ++ni) {
        const int cn = n0 + wn + ni * 16 + fr;
#pragma unroll
        for (int mi = 0; mi < 2; ++mi) {
            const int rm = m0 + wm + mi * 16 + rbase;
#pragma unroll
            for (int rr = 0; rr < 4; ++rr)
                C[(size_t)(rm + rr) * Ec + cn] = acc[mi][ni][rr];
        }
    }
}

// out = Cp0 + Cp1 + bias  (memory-bound, 576 blocks)
__global__ __launch_bounds__(256) void addbias_kernel(
    const float* __restrict__ Cp, const float* __restrict__ bias,
    float* __restrict__ out)
{
    const size_t MAT = (size_t)(Bc * Tc) * Ec;
    int i = blockIdx.x * 1024 + threadIdx.x * 4;
    float4 a = *reinterpret_cast<const float4*>(&Cp[i]);
    float4 b = *reinterpret_cast<const float4*>(&Cp[MAT + i]);
    float4 bs = *reinterpret_cast<const float4*>(&bias[i % Ec]);
    float4 r;
    r.x = a.x + b.x + bs.x;
    r.y = a.y + b.y + bs.y;
    r.z = a.z + b.z + bs.z;
    r.w = a.w + b.w + bs.w;
    *reinterpret_cast<float4*>(&out[i]) = r;
}

// ---------------------------------------------------------------------------
// score+softmax: S = sum_d w_d * rcp(1 + EQ*EK). Per-wave shape (R=2 t-rows,
// 1 s per lane), blockIdx.z splits s into thirds -> grid 3456 blocks
// (13.5/CU >= 8/CU LDS cap -> sustained high wave occupancy). Partial row
// sums -> Rpart[z]; pv adds all three (deterministic).
// ---------------------------------------------------------------------------
__global__ __launch_bounds__(256) void score_softmax_kernel(
    const float* __restrict__ EQ, const float* __restrict__ EK,
    const float* __restrict__ w_score,
    unsigned short* __restrict__ Pg, float* __restrict__ Rpart)
{
    const int bh = blockIdx.x;
    const int b = bh / Hc, h = bh % Hc;
    const int t0 = blockIdx.y * TTc;
    const int sbase = blockIdx.z * SHALF;
    const int tid = threadIdx.x;
    const int wave = tid >> 6, lane = tid & 63;

    __shared__ float qs[TTc][HDc];            // 2 KB (EQ tile)
    __shared__ float kv[SCc][HDc + 4];        // 17 KB (EK chunk, natural [s][d])

    {
        int r = tid >> 5, d2 = (tid & 31) << 1;
        float2 qv = *reinterpret_cast<const float2*>(
            &EQ[(size_t)(b * Tc + t0 + r) * Ec + h * HDc + d2]);
        qs[r][d2] = qv.x;
        qs[r][d2 + 1] = qv.y;
    }
    __syncthreads();

    const int ta = wave, tb = wave + 4;
    unsigned short* dstA = &Pg[((size_t)bh * Tc + t0 + ta) * Tc + sbase + lane];
    unsigned short* dstB = &Pg[((size_t)bh * Tc + t0 + tb) * Tc + sbase + lane];

    float sum0 = 0.f, sum1 = 0.f;

    for (int c = 0; c < NCHUNK; ++c) {
        const int s0 = sbase + c * SCc;
        if (c > 0) __syncthreads();
#pragma unroll
        for (int i = 0; i < 4; ++i) {
            int id = i * 256 + tid;
            int srr = id >> 4, d4 = (id & 15) << 2;
            float4 kvv = *reinterpret_cast<const float4*>(
                &EK[(size_t)(b * Tc + s0 + srr) * Ec + h * HDc + d4]);
            *reinterpret_cast<float4*>(&kv[srr][d4]) = kvv;
        }
        __syncthreads();
        float a0 = 0.f, a1 = 0.f;
#pragma unroll
        for (int d4 = 0; d4 < HDc; d4 += 4) {
            float4 k4 = *reinterpret_cast<const float4*>(&kv[lane][d4]);
            float4 qa = *reinterpret_cast<const float4*>(&qs[ta][d4]);
            float4 qb = *reinterpret_cast<const float4*>(&qs[tb][d4]);
            a0 = fmaf(w_score[d4 + 0], frcp(fmaf(qa.x, k4.x, 1.f)), a0);
            a0 = fmaf(w_score[d4 + 1], frcp(fmaf(qa.y, k4.y, 1.f)), a0);
            a0 = fmaf(w_score[d4 + 2], frcp(fmaf(qa.z, k4.z, 1.f)), a0);
            a0 = fmaf(w_score[d4 + 3], frcp(fmaf(qa.w, k4.w, 1.f)), a0);
            a1 = fmaf(w_score[d4 + 0], frcp(fmaf(qb.x, k4.x, 1.f)), a1);
            a1 = fmaf(w_score[d4 + 1], frcp(fmaf(qb.y, k4.y, 1.f)), a1);
            a1 = fmaf(w_score[d4 + 2], frcp(fmaf(qb.z, k4.z, 1.f)), a1);
            a1 = fmaf(w_score[d4 + 3], frcp(fmaf(qb.w, k4.w, 1.f)), a1);
        }
        // p = exp(-2S) = exp2(-S*cc); bounded in [2^-3, 2^3] -> no max pass
        float p0 = fexp2(-a0 * CCONST);
        float p1 = fexp2(-a1 * CCONST);
        dstA[c * SCc] = bf16_rne(p0);
        dstB[c * SCc] = bf16_rne(p1);
        sum0 += p0;
        sum1 += p1;
    }

    // partial row sums via wave butterfly; lane 0 writes this third's sum
#pragma unroll
    for (int off = 32; off > 0; off >>= 1) {
        sum0 += __shfl_xor(sum0, off, 64);
        sum1 += __shfl_xor(sum1, off, 64);
    }
    if (lane == 0) {
        Rpart[(size_t)blockIdx.z * BHT + bh * Tc + t0 + ta] = sum0;
        Rpart[(size_t)blockIdx.z * BHT + bh * Tc + t0 + tb] = sum1;
    }
}

// ---------------------------------------------------------------------------
// PV via MFMA on UNNORMALIZED p: out[t][d] = sum_s p*V / (sum of 3 Rparts).
// Per block 64t x 64d, 4 waves = m-split, no LDS. Emits ATT bf16 hi/lo.
// ---------------------------------------------------------------------------
__global__ __launch_bounds__(256) void pv_mfma(
    const unsigned short* __restrict__ Pg, const unsigned short* __restrict__ Vt,
    const float* __restrict__ Rpart,
    unsigned short* __restrict__ Ohi, unsigned short* __restrict__ Olo)
{
    const int bh = blockIdx.x;
    const int b = bh / Hc, h = bh % Hc;
    const int tt = blockIdx.y;  // 0..5
    const int tid = threadIdx.x;
    const int wave = tid >> 6, lane = tid & 63;
    const int fr = lane & 15, fk = (lane >> 4) * 8;

    const unsigned short* Pbase = Pg + ((size_t)bh * Tc + tt * 64 + wave * 16 + fr) * Tc + fk;
    const unsigned short* Vbase = Vt + (size_t)bh * HDc * Tc + fk;

    f32x4 zero = {0.f, 0.f, 0.f, 0.f};
    f32x4 acc[4];
    acc[0] = zero; acc[1] = zero; acc[2] = zero; acc[3] = zero;

    for (int ks = 0; ks < Tc; ks += 32) {
        short8 af = *reinterpret_cast<const short8*>(Pbase + ks);
#pragma unroll
        for (int ni = 0; ni < 4; ++ni) {
            short8 bf = *reinterpret_cast<const short8*>(
                Vbase + (size_t)(ni * 16 + fr) * Tc + ks);
            acc[ni] = __builtin_amdgcn_mfma_f32_16x16x32_bf16(af, bf, acc[ni], 0, 0, 0);
        }
    }

    const int rbase = (lane >> 4) * 4;
    float rv[4];
#pragma unroll
    for (int rr = 0; rr < 4; ++rr) {
        size_t ridx = (size_t)bh * Tc + tt * 64 + wave * 16 + rbase + rr;
        rv[rr] = frcp(Rpart[ridx] + Rpart[ridx + BHT] + Rpart[ridx + 2 * BHT]);
    }

#pragma unroll
    for (int ni = 0; ni < 4; ++ni) {
#pragma unroll
        for (int rr = 0; rr < 4; ++rr) {
            int t_out = tt * 64 + wave * 16 + rbase + rr;
            float x = acc[ni][rr] * rv[rr];
            unsigned short hb = bf16_rne(x);
            unsigned short lb = bf16_rne(x - bf16_to_f(hb));
            size_t idx = (size_t)(b * Tc + t_out) * Ec + h * HDc + ni * 16 + fr;
            Ohi[idx] = hb;
            Olo[idx] = lb;
        }
    }
}

extern "C" void kernel_launch(void* const* d_in, const int* in_sizes, int n_in,
                              void* d_out, int out_size, void* d_ws, size_t ws_size,
                              hipStream_t stream) {
    const float* hs  = (const float*)d_in[0];
    const float* Wq  = (const float*)d_in[1];
    const float* bq  = (const float*)d_in[2];
    const float* Wk  = (const float*)d_in[3];
    const float* bk  = (const float*)d_in[4];
    const float* Wv  = (const float*)d_in[5];
    const float* bv  = (const float*)d_in[6];
    const float* Wo  = (const float*)d_in[7];
    const float* bo  = (const float*)d_in[8];
    const float* wsc = (const float*)d_in[9];
    float* out = (float*)d_out;

    const size_t MAT = (size_t)(Bc * Tc) * Ec;           // 589824
    const size_t PSZ = (size_t)Bc * Hc * Tc * Tc;        // 3538944
    float* EQw = (float*)d_ws;                           // exp2(cc*q); later Cpart[0]
    float* EKw = EQw + MAT;                              // exp2(cc*k); later Cpart[1]
    float* Rpart = EKw + MAT;                            // partial rowsums, 3 x BHT
    unsigned short* Vt    = (unsigned short*)(Rpart + 3 * (size_t)BHT);
    unsigned short* Pgb   = Vt + MAT;
    unsigned short* HS_HI = Pgb + PSZ;
    unsigned short* HS_LO = HS_HI + MAT;                 // reused as ATT hi/lo
    unsigned short* WT_HI = HS_LO + MAT;
    unsigned short* WT_LO = WT_HI + 4 * MAT;

    prep_kernel<<<720, 256, 0, stream>>>(hs, Wq, Wk, Wv, Wo, HS_HI, WT_HI, WT_LO);

    gemm_qkv<<<dim3(Ec / 64, (Bc * Tc) / 64, 3), 256, 0, stream>>>(
        HS_HI,
        WT_HI + 0 * MAT, WT_HI + 1 * MAT, WT_HI + 2 * MAT,
        bq, bk, bv, EQw, EKw, Vt);

    score_softmax_kernel<<<dim3(Bc * Hc, Tc / TTc, SSPLIT), 256, 0, stream>>>(
        EQw, EKw, wsc, Pgb, Rpart);

    pv_mfma<<<dim3(Bc * Hc, Tc / 64), 256, 0, stream>>>(Pgb, Vt, Rpart, HS_HI, HS_LO);

    // EQ/EK are dead now; reuse their 2*MAT floats as the K-split partials.
    gemm_out<<<dim3(Ec / 64, (Bc * Tc) / 64, 2), 256, 0, stream>>>(
        HS_HI, HS_LO,
        WT_HI + 3 * MAT, WT_LO + 3 * MAT,
        EQw);

    addbias_kernel<<<(int)(MAT / 1024), 256, 0, stream>>>(EQw, bo, out);
}